// Round 16
// baseline (250.614 us; speedup 1.0000x reference)
//
#include <hip/hip_runtime.h>
#include <hip/hip_bf16.h>

typedef unsigned short u16;
typedef unsigned int   u32;

#define N_NODES 10000
#define N_EDGES 80000

// ---------- bf16 workspace helpers (math = fp32, ws storage = bf16) ----------
__device__ __forceinline__ u16 f2bf(float f) {   // round-to-nearest-even
    union { float f; u32 i; } c; c.f = f;
    u32 u = c.i;
    u32 r = (u + 0x7fffu + ((u >> 16) & 1u)) >> 16;
    return (u16)r;
}
__device__ __forceinline__ float bf2f(u16 u) {
    union { u32 i; float f; } c; c.i = ((u32)u) << 16; return c.f;
}
__device__ __forceinline__ void unpack8(uint4 w, float* v) {
    union { u32 i; float f; } c;
    c.i = w.x << 16; v[0] = c.f; c.i = w.x & 0xffff0000u; v[1] = c.f;
    c.i = w.y << 16; v[2] = c.f; c.i = w.y & 0xffff0000u; v[3] = c.f;
    c.i = w.z << 16; v[4] = c.f; c.i = w.z & 0xffff0000u; v[5] = c.f;
    c.i = w.w << 16; v[6] = c.f; c.i = w.w & 0xffff0000u; v[7] = c.f;
}

// =====================================================================
// proj1: out(N x 512, bf16 ws) = x(N x 64) @ W^T(512 x 64) + b
// =====================================================================
__global__ __launch_bounds__(256) void proj1_kernel(
    const float* __restrict__ x, const float* __restrict__ W,
    const float* __restrict__ b, u16* __restrict__ out)
{
    __shared__ float xs[64 * 68];
    __shared__ float wt[64 * 68];
    const int t  = threadIdx.x;
    const int r0 = blockIdx.x * 64;
    const int c0 = blockIdx.y * 64;

    {
        const int row = t >> 2, seg = t & 3;
        const int r = r0 + row;
        if (r < N_NODES) {
            const float4* p = (const float4*)(x + ((long)r * 64 + seg * 16));
            #pragma unroll
            for (int q4 = 0; q4 < 4; ++q4) *(float4*)&xs[row * 68 + seg * 16 + q4 * 4] = p[q4];
        } else {
            #pragma unroll
            for (int j = 0; j < 16; ++j) xs[row * 68 + seg * 16 + j] = 0.f;
        }
        const float4* q = (const float4*)(W + ((long)(c0 + row) * 64 + seg * 16));
        #pragma unroll
        for (int q4 = 0; q4 < 4; ++q4) *(float4*)&wt[row * 68 + seg * 16 + q4 * 4] = q[q4];
    }
    __syncthreads();

    const int tc = t & 15, tr = t >> 4;
    float acc[4][4];
    #pragma unroll
    for (int r = 0; r < 4; ++r)
        #pragma unroll
        for (int c = 0; c < 4; ++c) acc[r][c] = 0.f;

    #pragma unroll 4
    for (int k4 = 0; k4 < 16; ++k4) {
        float4 a[4], b4[4];
        #pragma unroll
        for (int r = 0; r < 4; ++r) a[r] = *(const float4*)&xs[(tr * 4 + r) * 68 + k4 * 4];
        #pragma unroll
        for (int c = 0; c < 4; ++c) b4[c] = *(const float4*)&wt[(tc * 4 + c) * 68 + k4 * 4];
        #pragma unroll
        for (int r = 0; r < 4; ++r)
            #pragma unroll
            for (int c = 0; c < 4; ++c)
                acc[r][c] += a[r].x * b4[c].x + a[r].y * b4[c].y + a[r].z * b4[c].z + a[r].w * b4[c].w;
    }

    #pragma unroll
    for (int r = 0; r < 4; ++r) {
        const int gr = r0 + tr * 4 + r;
        if (gr >= N_NODES) continue;
        const int cb = c0 + tc * 4;
        float v0 = acc[r][0] + b[cb + 0];
        float v1 = acc[r][1] + b[cb + 1];
        float v2 = acc[r][2] + b[cb + 2];
        float v3 = acc[r][3] + b[cb + 3];
        u32 p0 = (u32)f2bf(v0) | ((u32)f2bf(v1) << 16);
        u32 p1 = (u32)f2bf(v2) | ((u32)f2bf(v3) << 16);
        *(uint2*)(out + (long)gr * 512 + cb) = make_uint2(p0, p1);
    }
}

// =====================================================================
// gfold: in-place: G[m][h*64+c] = sum_d C[m][h*64+d] * Wlin[c][h*64+d]
// (folds the final Wlin GEMM into per-node value rows; block-exclusive tiles)
// =====================================================================
__global__ __launch_bounds__(256) void gfold_kernel(
    u16* __restrict__ C, const float* __restrict__ Wlin)
{
    __shared__ float aa[64 * 68];
    __shared__ float bb[64 * 68];
    const int t  = threadIdx.x;
    const int r0 = blockIdx.x * 64;
    const int h  = blockIdx.y;

    {
        const int row = t >> 2, seg = t & 3;
        const int r = r0 + row;
        if (r < N_NODES) {
            const uint4* p = (const uint4*)(C + ((long)r * 512 + h * 64 + seg * 16));
            float v[16]; unpack8(p[0], v); unpack8(p[1], v + 8);
            #pragma unroll
            for (int j = 0; j < 16; ++j) aa[row * 68 + seg * 16 + j] = v[j];
        } else {
            #pragma unroll
            for (int j = 0; j < 16; ++j) aa[row * 68 + seg * 16 + j] = 0.f;
        }
        const float4* q = (const float4*)(Wlin + ((long)row * 512 + h * 64 + seg * 16));
        #pragma unroll
        for (int q4 = 0; q4 < 4; ++q4) *(float4*)&bb[row * 68 + seg * 16 + q4 * 4] = q[q4];
    }
    __syncthreads();

    const int tc = t & 15, tr = t >> 4;
    float acc[4][4];
    #pragma unroll
    for (int r = 0; r < 4; ++r)
        #pragma unroll
        for (int c = 0; c < 4; ++c) acc[r][c] = 0.f;

    #pragma unroll 4
    for (int k4 = 0; k4 < 16; ++k4) {
        float4 a[4], b4[4];
        #pragma unroll
        for (int r = 0; r < 4; ++r) a[r] = *(const float4*)&aa[(tr * 4 + r) * 68 + k4 * 4];
        #pragma unroll
        for (int c = 0; c < 4; ++c) b4[c] = *(const float4*)&bb[(tc * 4 + c) * 68 + k4 * 4];
        #pragma unroll
        for (int r = 0; r < 4; ++r)
            #pragma unroll
            for (int c = 0; c < 4; ++c)
                acc[r][c] += a[r].x * b4[c].x + a[r].y * b4[c].y + a[r].z * b4[c].z + a[r].w * b4[c].w;
    }

    #pragma unroll
    for (int r = 0; r < 4; ++r) {
        const int gr = r0 + tr * 4 + r;
        if (gr >= N_NODES) continue;
        const int cb = h * 64 + tc * 4;
        u32 p0 = (u32)f2bf(acc[r][0]) | ((u32)f2bf(acc[r][1]) << 16);
        u32 p1 = (u32)f2bf(acc[r][2]) | ((u32)f2bf(acc[r][3]) << 16);
        *(uint2*)(C + (long)gr * 512 + cb) = make_uint2(p0, p1);
    }
}

// =====================================================================
// sqk (displayed): sq[e=n*8+i, h] = dot64(q[n,h,:], k[e1[e],h,:]) / 8
// Per 64-node block: recompute q head-by-head, dot vs bf16 NK rows.
// =====================================================================
__global__ __launch_bounds__(256) void sqk_kernel(
    const float* __restrict__ x, const float* __restrict__ Wq, const float* __restrict__ bq,
    const u16* __restrict__ NK, const int* __restrict__ e1, float* __restrict__ sq)
{
    __shared__ float xs[64 * 68];
    __shared__ float wqh[64 * 68];
    __shared__ float qh[64 * 68];
    __shared__ int   tg[512];
    const int t  = threadIdx.x;
    const int n0 = blockIdx.x * 64;

    {
        const int row = t >> 2, seg = t & 3;
        const int r = n0 + row;
        if (r < N_NODES) {
            const float4* p = (const float4*)(x + ((long)r * 64 + seg * 16));
            #pragma unroll
            for (int q4 = 0; q4 < 4; ++q4) *(float4*)&xs[row * 68 + seg * 16 + q4 * 4] = p[q4];
        } else {
            #pragma unroll
            for (int j = 0; j < 16; ++j) xs[row * 68 + seg * 16 + j] = 0.f;
        }
        int i0 = t, i1 = t + 256;
        tg[i0] = (n0 * 8 + i0 < N_EDGES) ? e1[n0 * 8 + i0] : 0;
        tg[i1] = (n0 * 8 + i1 < N_EDGES) ? e1[n0 * 8 + i1] : 0;
    }
    __syncthreads();

    const int tc = t & 15, tr = t >> 4;

    for (int h = 0; h < 8; ++h) {
        {
            const int row = t >> 2, seg = t & 3;
            const float4* q = (const float4*)(Wq + ((long)(h * 64 + row) * 64 + seg * 16));
            #pragma unroll
            for (int q4 = 0; q4 < 4; ++q4) *(float4*)&wqh[row * 68 + seg * 16 + q4 * 4] = q[q4];
        }
        __syncthreads();

        float acc[4][4];
        #pragma unroll
        for (int r = 0; r < 4; ++r)
            #pragma unroll
            for (int c = 0; c < 4; ++c) acc[r][c] = 0.f;
        #pragma unroll 4
        for (int k4 = 0; k4 < 16; ++k4) {
            float4 a[4], b4[4];
            #pragma unroll
            for (int r = 0; r < 4; ++r) a[r] = *(const float4*)&xs[(tr * 4 + r) * 68 + k4 * 4];
            #pragma unroll
            for (int c = 0; c < 4; ++c) b4[c] = *(const float4*)&wqh[(tc * 4 + c) * 68 + k4 * 4];
            #pragma unroll
            for (int r = 0; r < 4; ++r)
                #pragma unroll
                for (int c = 0; c < 4; ++c)
                    acc[r][c] += a[r].x * b4[c].x + a[r].y * b4[c].y + a[r].z * b4[c].z + a[r].w * b4[c].w;
        }
        #pragma unroll
        for (int r = 0; r < 4; ++r)
            #pragma unroll
            for (int c = 0; c < 4; ++c)
                qh[(tr * 4 + r) * 68 + tc * 4 + c] = acc[r][c] + bq[h * 64 + tc * 4 + c];
        __syncthreads();

        #pragma unroll
        for (int rep = 0; rep < 2; ++rep) {
            const int p = rep * 256 + t;
            const int nl = p >> 3, i = p & 7;
            if (n0 + nl < N_NODES) {
                const int kr = tg[p];
                const uint4* kp = (const uint4*)(NK + ((long)kr * 512 + h * 64));
                float d = 0.f;
                #pragma unroll
                for (int q4 = 0; q4 < 8; ++q4) {
                    float kv[8]; unpack8(kp[q4], kv);
                    const float* qp = &qh[nl * 68 + q4 * 8];
                    #pragma unroll
                    for (int j = 0; j < 8; ++j) d += qp[j] * kv[j];
                }
                sq[(long)(n0 + nl) * 64 + i * 8 + h] = d * 0.125f;
            }
        }
        __syncthreads();
    }
}

// =====================================================================
// node kernel: one block (64 threads) per node; displayed semantics.
// Outputs written as FLOAT32.
// =====================================================================
__global__ __launch_bounds__(64) void node_kernel(
    const float* __restrict__ ef, const int* __restrict__ e1,
    const float* __restrict__ sq, const u16* __restrict__ G,
    const float* __restrict__ Weq, const float* __restrict__ beq,
    const float* __restrict__ Wev, const float* __restrict__ bev,
    const float* __restrict__ Wek, const float* __restrict__ bek,
    const float* __restrict__ Wel, const float* __restrict__ bel,
    const float* __restrict__ Wele, const float* __restrict__ bele,
    const float* __restrict__ blin,
    float* __restrict__ out_node, float* __restrict__ out_edge)
{
    __shared__ float sqk_l[64];
    __shared__ float efl[128];
    __shared__ float eqb[8 * 68], ekb[8 * 68], evb[8 * 68], eob[8 * 68];
    __shared__ float sl[8 * 36];
    __shared__ float well[8 * 65];
    __shared__ float emb_l[64];
    __shared__ float attn_l[64];
    __shared__ int   tgt[8];

    const int t = threadIdx.x;
    const int n = blockIdx.x;

    if (t < 8) tgt[t] = e1[n * 8 + t];
    sqk_l[t] = sq[(long)n * 64 + t];
    {
        const float2* p = (const float2*)(ef + (long)n * 128);
        float2 w = p[t];
        efl[2 * t] = w.x; efl[2 * t + 1] = w.y;
    }
    for (int idx = t; idx < 512; idx += 64)
        well[(idx >> 6) * 65 + (idx & 63)] = Wel[idx];
    __syncthreads();

    float wq16[16], wv16[16], wk8[8];
    {
        const float4* p = (const float4*)(Weq + t * 16);
        #pragma unroll
        for (int q4 = 0; q4 < 4; ++q4) *(float4*)&wq16[q4 * 4] = p[q4];
        const float4* q = (const float4*)(Wev + t * 16);
        #pragma unroll
        for (int q4 = 0; q4 < 4; ++q4) *(float4*)&wv16[q4 * 4] = q[q4];
        const float4* r = (const float4*)(Wek + t * 8);
        *(float4*)&wk8[0] = r[0]; *(float4*)&wk8[4] = r[1];
    }
    const float beqv = beq[t], bevv = bev[t], bekv = bek[t];

    #pragma unroll
    for (int i = 0; i < 8; ++i) {
        float aq = beqv, av = bevv;
        #pragma unroll
        for (int c = 0; c < 16; ++c) { float f = efl[i * 16 + c]; aq += f * wq16[c]; av += f * wv16[c]; }
        float ak = bekv;
        #pragma unroll
        for (int c = 0; c < 8; ++c) ak += sqk_l[i * 8 + c] * wk8[c];
        eqb[i * 68 + t] = aq; evb[i * 68 + t] = av; ekb[i * 68 + t] = ak;
    }
    __syncthreads();

    {
        const int i = t >> 3, j = t & 7;
        #pragma unroll
        for (int eh = 0; eh < 4; ++eh) {
            float acc = 0.f;
            #pragma unroll
            for (int de = 0; de < 16; ++de)
                acc += eqb[i * 68 + eh * 16 + de] * ekb[j * 68 + eh * 16 + de];
            sl[i * 36 + j * 4 + eh] = acc * 0.25f;
        }
    }
    __syncthreads();

    if (t < 32) {
        const int i = t >> 2, eh = t & 3;
        float mx = -1e30f;
        #pragma unroll
        for (int j = 0; j < 8; ++j) mx = fmaxf(mx, sl[i * 36 + j * 4 + eh]);
        float sum = 0.f;
        #pragma unroll
        for (int j = 0; j < 8; ++j) { float e = __expf(sl[i * 36 + j * 4 + eh] - mx); sl[i * 36 + j * 4 + eh] = e; sum += e; }
        float inv = 1.f / (sum + 1e-16f);
        #pragma unroll
        for (int j = 0; j < 8; ++j) sl[i * 36 + j * 4 + eh] *= inv;
    }
    __syncthreads();

    {
        const int eh = t >> 4;
        #pragma unroll
        for (int i = 0; i < 8; ++i) {
            float acc = 0.f;
            #pragma unroll
            for (int j = 0; j < 8; ++j) acc += sl[i * 36 + j * 4 + eh] * evb[j * 68 + t];
            eob[i * 68 + t] = acc;
        }
    }
    __syncthreads();

    {
        const int i = t >> 3, h = t & 7;
        float acc = bel[h];
        #pragma unroll 8
        for (int c = 0; c < 64; ++c) acc += eob[i * 68 + c] * well[h * 65 + c];
        emb_l[i * 8 + h] = acc;
    }
    __syncthreads();

    #pragma unroll
    for (int rep = 0; rep < 2; ++rep) {
        const int idx = rep * 64 + t;
        const int i = idx >> 4, de = idx & 15;
        float acc = bele[de];
        #pragma unroll
        for (int h = 0; h < 8; ++h) acc += emb_l[i * 8 + h] * Wele[de * 8 + h];
        out_edge[(long)n * 128 + idx] = acc;          // FLOAT32 out
    }

    if (t < 8) {
        const int h = t;
        float l[8], mx = -1e30f;
        #pragma unroll
        for (int i = 0; i < 8; ++i) { l[i] = emb_l[i * 8 + h] + sqk_l[i * 8 + h]; mx = fmaxf(mx, l[i]); }
        float sum = 0.f;
        #pragma unroll
        for (int i = 0; i < 8; ++i) { float e = __expf(l[i] - mx); attn_l[i * 8 + h] = e; sum += e; }
        float inv = 1.f / (sum + 1e-16f);
        #pragma unroll
        for (int i = 0; i < 8; ++i) attn_l[i * 8 + h] *= inv;
    }
    __syncthreads();

    {
        float acc = blin[t];
        #pragma unroll
        for (int i = 0; i < 8; ++i) {
            const u16* gr = G + (long)tgt[i] * 512;
            #pragma unroll
            for (int h = 0; h < 8; ++h)
                acc += attn_l[i * 8 + h] * bf2f(gr[h * 64 + t]);
        }
        out_node[(long)n * 64 + t] = acc;             // FLOAT32 out
    }
}

extern "C" void kernel_launch(void* const* d_in, const int* in_sizes, int n_in,
                              void* d_out, int out_size, void* d_ws, size_t ws_size,
                              hipStream_t stream) {
    (void)in_sizes; (void)n_in; (void)out_size; (void)ws_size;
    const float* x    = (const float*)d_in[0];
    const float* ef   = (const float*)d_in[1];
    const float* Wq   = (const float*)d_in[2];
    const float* bq   = (const float*)d_in[3];
    const float* Wk   = (const float*)d_in[4];
    const float* bk   = (const float*)d_in[5];
    const float* Wv   = (const float*)d_in[6];
    const float* bv   = (const float*)d_in[7];
    const float* Wlin = (const float*)d_in[8];
    const float* blin = (const float*)d_in[9];
    const float* Weq  = (const float*)d_in[10];
    const float* beq  = (const float*)d_in[11];
    const float* Wev  = (const float*)d_in[12];
    const float* bev  = (const float*)d_in[13];
    const float* Wek  = (const float*)d_in[14];
    const float* bek  = (const float*)d_in[15];
    const float* Wel  = (const float*)d_in[16];
    const float* bel  = (const float*)d_in[17];
    const float* Wele = (const float*)d_in[18];
    const float* bele = (const float*)d_in[19];
    const int* edge_index = (const int*)d_in[20];
    const int* e1 = edge_index + N_EDGES;   // row1 = targets

    float* out_node = (float*)d_out;            // N x 64 fp32
    float* out_edge = (float*)d_out + 640000;   // E x 16 fp32

    // ws: NK bf16 [0,10.24MB) | C->G bf16 [10.24,20.48) | sq fp32 [20.48,23.04)
    char* ws = (char*)d_ws;
    u16*   NK = (u16*)ws;
    u16*   G  = (u16*)(ws + 10240000);
    float* sq = (float*)(ws + 20480000);

    proj1_kernel<<<dim3(157, 8), 256, 0, stream>>>(x, Wk, bk, NK);
    proj1_kernel<<<dim3(157, 8), 256, 0, stream>>>(x, Wv, bv, G);
    gfold_kernel<<<dim3(157, 8), 256, 0, stream>>>(G, Wlin);
    sqk_kernel<<<157, 256, 0, stream>>>(x, Wq, bq, NK, e1, sq);
    node_kernel<<<N_NODES, 64, 0, stream>>>(ef, e1, sq, G,
                                            Weq, beq, Wev, bev, Wek, bek,
                                            Wel, bel, Wele, bele, blin,
                                            out_node, out_edge);
}

// Round 17
// 223.568 us; speedup vs baseline: 1.1210x; 1.1210x over previous
//
#include <hip/hip_runtime.h>
#include <hip/hip_bf16.h>

typedef unsigned short u16;
typedef unsigned int   u32;

#define N_NODES 10000
#define N_EDGES 80000

// ---------- bf16 workspace helpers (math = fp32, ws storage = bf16) ----------
__device__ __forceinline__ u16 f2bf(float f) {   // round-to-nearest-even
    union { float f; u32 i; } c; c.f = f;
    u32 u = c.i;
    u32 r = (u + 0x7fffu + ((u >> 16) & 1u)) >> 16;
    return (u16)r;
}
__device__ __forceinline__ float bf2f(u16 u) {
    union { u32 i; float f; } c; c.i = ((u32)u) << 16; return c.f;
}
__device__ __forceinline__ void unpack8(uint4 w, float* v) {
    union { u32 i; float f; } c;
    c.i = w.x << 16; v[0] = c.f; c.i = w.x & 0xffff0000u; v[1] = c.f;
    c.i = w.y << 16; v[2] = c.f; c.i = w.y & 0xffff0000u; v[3] = c.f;
    c.i = w.z << 16; v[4] = c.f; c.i = w.z & 0xffff0000u; v[5] = c.f;
    c.i = w.w << 16; v[6] = c.f; c.i = w.w & 0xffff0000u; v[7] = c.f;
}

// =====================================================================
// proj2: one dispatch for BOTH nk (Wk) and nv (Wv) projections.
// grid (157, 16): y<8 -> NK tile, y>=8 -> NV(G) tile.
// out(N x 512, bf16 ws) = x(N x 64) @ W^T(512 x 64) + b
// =====================================================================
__global__ __launch_bounds__(256) void proj2_kernel(
    const float* __restrict__ x,
    const float* __restrict__ Wk, const float* __restrict__ bk,
    const float* __restrict__ Wv, const float* __restrict__ bv,
    u16* __restrict__ NK, u16* __restrict__ NV)
{
    __shared__ float xs[64 * 68];
    __shared__ float wt[64 * 68];
    const int t   = threadIdx.x;
    const int r0  = blockIdx.x * 64;
    const int cy  = blockIdx.y;
    const int mat = cy >> 3;
    const int c0  = (cy & 7) * 64;
    const float* W  = mat ? Wv : Wk;
    const float* bb = mat ? bv : bk;
    u16*       outp = mat ? NV : NK;

    {
        const int row = t >> 2, seg = t & 3;
        const int r = r0 + row;
        if (r < N_NODES) {
            const float4* p = (const float4*)(x + ((long)r * 64 + seg * 16));
            #pragma unroll
            for (int q4 = 0; q4 < 4; ++q4) *(float4*)&xs[row * 68 + seg * 16 + q4 * 4] = p[q4];
        } else {
            #pragma unroll
            for (int j = 0; j < 16; ++j) xs[row * 68 + seg * 16 + j] = 0.f;
        }
        const float4* q = (const float4*)(W + ((long)(c0 + row) * 64 + seg * 16));
        #pragma unroll
        for (int q4 = 0; q4 < 4; ++q4) *(float4*)&wt[row * 68 + seg * 16 + q4 * 4] = q[q4];
    }
    __syncthreads();

    const int tc = t & 15, tr = t >> 4;
    float acc[4][4];
    #pragma unroll
    for (int r = 0; r < 4; ++r)
        #pragma unroll
        for (int c = 0; c < 4; ++c) acc[r][c] = 0.f;

    #pragma unroll 4
    for (int k4 = 0; k4 < 16; ++k4) {
        float4 a[4], b4[4];
        #pragma unroll
        for (int r = 0; r < 4; ++r) a[r] = *(const float4*)&xs[(tr * 4 + r) * 68 + k4 * 4];
        #pragma unroll
        for (int c = 0; c < 4; ++c) b4[c] = *(const float4*)&wt[(tc * 4 + c) * 68 + k4 * 4];
        #pragma unroll
        for (int r = 0; r < 4; ++r)
            #pragma unroll
            for (int c = 0; c < 4; ++c)
                acc[r][c] += a[r].x * b4[c].x + a[r].y * b4[c].y + a[r].z * b4[c].z + a[r].w * b4[c].w;
    }

    #pragma unroll
    for (int r = 0; r < 4; ++r) {
        const int gr = r0 + tr * 4 + r;
        if (gr >= N_NODES) continue;
        const int cb = c0 + tc * 4;
        float v0 = acc[r][0] + bb[cb + 0];
        float v1 = acc[r][1] + bb[cb + 1];
        float v2 = acc[r][2] + bb[cb + 2];
        float v3 = acc[r][3] + bb[cb + 3];
        u32 p0 = (u32)f2bf(v0) | ((u32)f2bf(v1) << 16);
        u32 p1 = (u32)f2bf(v2) | ((u32)f2bf(v3) << 16);
        *(uint2*)(outp + (long)gr * 512 + cb) = make_uint2(p0, p1);
    }
}

// =====================================================================
// gfold: in-place: G[m][h*64+c] = sum_d C[m][h*64+d] * Wlin[c][h*64+d]
// =====================================================================
__global__ __launch_bounds__(256) void gfold_kernel(
    u16* __restrict__ C, const float* __restrict__ Wlin)
{
    __shared__ float aa[64 * 68];
    __shared__ float bb[64 * 68];
    const int t  = threadIdx.x;
    const int r0 = blockIdx.x * 64;
    const int h  = blockIdx.y;

    {
        const int row = t >> 2, seg = t & 3;
        const int r = r0 + row;
        if (r < N_NODES) {
            const uint4* p = (const uint4*)(C + ((long)r * 512 + h * 64 + seg * 16));
            float v[16]; unpack8(p[0], v); unpack8(p[1], v + 8);
            #pragma unroll
            for (int j = 0; j < 16; ++j) aa[row * 68 + seg * 16 + j] = v[j];
        } else {
            #pragma unroll
            for (int j = 0; j < 16; ++j) aa[row * 68 + seg * 16 + j] = 0.f;
        }
        const float4* q = (const float4*)(Wlin + ((long)row * 512 + h * 64 + seg * 16));
        #pragma unroll
        for (int q4 = 0; q4 < 4; ++q4) *(float4*)&bb[row * 68 + seg * 16 + q4 * 4] = q[q4];
    }
    __syncthreads();

    const int tc = t & 15, tr = t >> 4;
    float acc[4][4];
    #pragma unroll
    for (int r = 0; r < 4; ++r)
        #pragma unroll
        for (int c = 0; c < 4; ++c) acc[r][c] = 0.f;

    #pragma unroll 4
    for (int k4 = 0; k4 < 16; ++k4) {
        float4 a[4], b4[4];
        #pragma unroll
        for (int r = 0; r < 4; ++r) a[r] = *(const float4*)&aa[(tr * 4 + r) * 68 + k4 * 4];
        #pragma unroll
        for (int c = 0; c < 4; ++c) b4[c] = *(const float4*)&bb[(tc * 4 + c) * 68 + k4 * 4];
        #pragma unroll
        for (int r = 0; r < 4; ++r)
            #pragma unroll
            for (int c = 0; c < 4; ++c)
                acc[r][c] += a[r].x * b4[c].x + a[r].y * b4[c].y + a[r].z * b4[c].z + a[r].w * b4[c].w;
    }

    #pragma unroll
    for (int r = 0; r < 4; ++r) {
        const int gr = r0 + tr * 4 + r;
        if (gr >= N_NODES) continue;
        const int cb = h * 64 + tc * 4;
        u32 p0 = (u32)f2bf(acc[r][0]) | ((u32)f2bf(acc[r][1]) << 16);
        u32 p1 = (u32)f2bf(acc[r][2]) | ((u32)f2bf(acc[r][3]) << 16);
        *(uint2*)(C + (long)gr * 512 + cb) = make_uint2(p0, p1);
    }
}

// =====================================================================
// sqk v2: grid (157 node-tiles, 8 heads) — one head per block, no loop.
//   sq[e=n*8+i, h] = dot64(q[n,h,:], k[e1[e],h,:]) / 8
// =====================================================================
__global__ __launch_bounds__(256) void sqk_kernel(
    const float* __restrict__ x, const float* __restrict__ Wq, const float* __restrict__ bq,
    const u16* __restrict__ NK, const int* __restrict__ e1, float* __restrict__ sq)
{
    __shared__ float xs[64 * 68];
    __shared__ float wqh[64 * 68];
    __shared__ float qh[64 * 68];
    __shared__ int   tg[512];
    const int t  = threadIdx.x;
    const int n0 = blockIdx.x * 64;
    const int h  = blockIdx.y;

    {
        const int row = t >> 2, seg = t & 3;
        const int r = n0 + row;
        if (r < N_NODES) {
            const float4* p = (const float4*)(x + ((long)r * 64 + seg * 16));
            #pragma unroll
            for (int q4 = 0; q4 < 4; ++q4) *(float4*)&xs[row * 68 + seg * 16 + q4 * 4] = p[q4];
        } else {
            #pragma unroll
            for (int j = 0; j < 16; ++j) xs[row * 68 + seg * 16 + j] = 0.f;
        }
        // Wq rows for this head
        const float4* q = (const float4*)(Wq + ((long)(h * 64 + row) * 64 + seg * 16));
        #pragma unroll
        for (int q4 = 0; q4 < 4; ++q4) *(float4*)&wqh[row * 68 + seg * 16 + q4 * 4] = q[q4];

        int i0 = t, i1 = t + 256;
        tg[i0] = (n0 * 8 + i0 < N_EDGES) ? e1[n0 * 8 + i0] : 0;
        tg[i1] = (n0 * 8 + i1 < N_EDGES) ? e1[n0 * 8 + i1] : 0;
    }
    __syncthreads();

    const int tc = t & 15, tr = t >> 4;
    float acc[4][4];
    #pragma unroll
    for (int r = 0; r < 4; ++r)
        #pragma unroll
        for (int c = 0; c < 4; ++c) acc[r][c] = 0.f;
    #pragma unroll 4
    for (int k4 = 0; k4 < 16; ++k4) {
        float4 a[4], b4[4];
        #pragma unroll
        for (int r = 0; r < 4; ++r) a[r] = *(const float4*)&xs[(tr * 4 + r) * 68 + k4 * 4];
        #pragma unroll
        for (int c = 0; c < 4; ++c) b4[c] = *(const float4*)&wqh[(tc * 4 + c) * 68 + k4 * 4];
        #pragma unroll
        for (int r = 0; r < 4; ++r)
            #pragma unroll
            for (int c = 0; c < 4; ++c)
                acc[r][c] += a[r].x * b4[c].x + a[r].y * b4[c].y + a[r].z * b4[c].z + a[r].w * b4[c].w;
    }
    #pragma unroll
    for (int r = 0; r < 4; ++r)
        #pragma unroll
        for (int c = 0; c < 4; ++c)
            qh[(tr * 4 + r) * 68 + tc * 4 + c] = acc[r][c] + bq[h * 64 + tc * 4 + c];
    __syncthreads();

    // 512 (node,edge) pairs; each thread 2
    #pragma unroll
    for (int rep = 0; rep < 2; ++rep) {
        const int p = rep * 256 + t;
        const int nl = p >> 3, i = p & 7;
        if (n0 + nl < N_NODES) {
            const int kr = tg[p];
            const uint4* kp = (const uint4*)(NK + ((long)kr * 512 + h * 64));
            float d = 0.f;
            #pragma unroll
            for (int q4 = 0; q4 < 8; ++q4) {
                float kv[8]; unpack8(kp[q4], kv);
                const float* qp = &qh[nl * 68 + q4 * 8];
                #pragma unroll
                for (int j = 0; j < 8; ++j) d += qp[j] * kv[j];
            }
            sq[(long)(n0 + nl) * 64 + i * 8 + h] = d * 0.125f;
        }
    }
}

// =====================================================================
// node kernel: one block (64 threads) per node; fp32 outputs.
// =====================================================================
__global__ __launch_bounds__(64) void node_kernel(
    const float* __restrict__ ef, const int* __restrict__ e1,
    const float* __restrict__ sq, const u16* __restrict__ G,
    const float* __restrict__ Weq, const float* __restrict__ beq,
    const float* __restrict__ Wev, const float* __restrict__ bev,
    const float* __restrict__ Wek, const float* __restrict__ bek,
    const float* __restrict__ Wel, const float* __restrict__ bel,
    const float* __restrict__ Wele, const float* __restrict__ bele,
    const float* __restrict__ blin,
    float* __restrict__ out_node, float* __restrict__ out_edge)
{
    __shared__ float sqk_l[64];
    __shared__ float efl[128];
    __shared__ float eqb[8 * 68], ekb[8 * 68], evb[8 * 68], eob[8 * 68];
    __shared__ float sl[8 * 36];
    __shared__ float well[8 * 65];
    __shared__ float emb_l[64];
    __shared__ float attn_l[64];
    __shared__ int   tgt[8];

    const int t = threadIdx.x;
    const int n = blockIdx.x;

    if (t < 8) tgt[t] = e1[n * 8 + t];
    sqk_l[t] = sq[(long)n * 64 + t];
    {
        const float2* p = (const float2*)(ef + (long)n * 128);
        float2 w = p[t];
        efl[2 * t] = w.x; efl[2 * t + 1] = w.y;
    }
    for (int idx = t; idx < 512; idx += 64)
        well[(idx >> 6) * 65 + (idx & 63)] = Wel[idx];
    __syncthreads();

    float wq16[16], wv16[16], wk8[8];
    {
        const float4* p = (const float4*)(Weq + t * 16);
        #pragma unroll
        for (int q4 = 0; q4 < 4; ++q4) *(float4*)&wq16[q4 * 4] = p[q4];
        const float4* q = (const float4*)(Wev + t * 16);
        #pragma unroll
        for (int q4 = 0; q4 < 4; ++q4) *(float4*)&wv16[q4 * 4] = q[q4];
        const float4* r = (const float4*)(Wek + t * 8);
        *(float4*)&wk8[0] = r[0]; *(float4*)&wk8[4] = r[1];
    }
    const float beqv = beq[t], bevv = bev[t], bekv = bek[t];

    #pragma unroll
    for (int i = 0; i < 8; ++i) {
        float aq = beqv, av = bevv;
        #pragma unroll
        for (int c = 0; c < 16; ++c) { float f = efl[i * 16 + c]; aq += f * wq16[c]; av += f * wv16[c]; }
        float ak = bekv;
        #pragma unroll
        for (int c = 0; c < 8; ++c) ak += sqk_l[i * 8 + c] * wk8[c];
        eqb[i * 68 + t] = aq; evb[i * 68 + t] = av; ekb[i * 68 + t] = ak;
    }
    __syncthreads();

    {
        const int i = t >> 3, j = t & 7;
        #pragma unroll
        for (int eh = 0; eh < 4; ++eh) {
            float acc = 0.f;
            #pragma unroll
            for (int de = 0; de < 16; ++de)
                acc += eqb[i * 68 + eh * 16 + de] * ekb[j * 68 + eh * 16 + de];
            sl[i * 36 + j * 4 + eh] = acc * 0.25f;
        }
    }
    __syncthreads();

    if (t < 32) {
        const int i = t >> 2, eh = t & 3;
        float mx = -1e30f;
        #pragma unroll
        for (int j = 0; j < 8; ++j) mx = fmaxf(mx, sl[i * 36 + j * 4 + eh]);
        float sum = 0.f;
        #pragma unroll
        for (int j = 0; j < 8; ++j) { float e = __expf(sl[i * 36 + j * 4 + eh] - mx); sl[i * 36 + j * 4 + eh] = e; sum += e; }
        float inv = 1.f / (sum + 1e-16f);
        #pragma unroll
        for (int j = 0; j < 8; ++j) sl[i * 36 + j * 4 + eh] *= inv;
    }
    __syncthreads();

    {
        const int eh = t >> 4;
        #pragma unroll
        for (int i = 0; i < 8; ++i) {
            float acc = 0.f;
            #pragma unroll
            for (int j = 0; j < 8; ++j) acc += sl[i * 36 + j * 4 + eh] * evb[j * 68 + t];
            eob[i * 68 + t] = acc;
        }
    }
    __syncthreads();

    {
        const int i = t >> 3, h = t & 7;
        float acc = bel[h];
        #pragma unroll 8
        for (int c = 0; c < 64; ++c) acc += eob[i * 68 + c] * well[h * 65 + c];
        emb_l[i * 8 + h] = acc;
    }
    __syncthreads();

    #pragma unroll
    for (int rep = 0; rep < 2; ++rep) {
        const int idx = rep * 64 + t;
        const int i = idx >> 4, de = idx & 15;
        float acc = bele[de];
        #pragma unroll
        for (int h = 0; h < 8; ++h) acc += emb_l[i * 8 + h] * Wele[de * 8 + h];
        out_edge[(long)n * 128 + idx] = acc;
    }

    if (t < 8) {
        const int h = t;
        float l[8], mx = -1e30f;
        #pragma unroll
        for (int i = 0; i < 8; ++i) { l[i] = emb_l[i * 8 + h] + sqk_l[i * 8 + h]; mx = fmaxf(mx, l[i]); }
        float sum = 0.f;
        #pragma unroll
        for (int i = 0; i < 8; ++i) { float e = __expf(l[i] - mx); attn_l[i * 8 + h] = e; sum += e; }
        float inv = 1.f / (sum + 1e-16f);
        #pragma unroll
        for (int i = 0; i < 8; ++i) attn_l[i * 8 + h] *= inv;
    }
    __syncthreads();

    {
        float acc = blin[t];
        #pragma unroll
        for (int i = 0; i < 8; ++i) {
            const u16* gr = G + (long)tgt[i] * 512;
            #pragma unroll
            for (int h = 0; h < 8; ++h)
                acc += attn_l[i * 8 + h] * bf2f(gr[h * 64 + t]);
        }
        out_node[(long)n * 64 + t] = acc;
    }
}

extern "C" void kernel_launch(void* const* d_in, const int* in_sizes, int n_in,
                              void* d_out, int out_size, void* d_ws, size_t ws_size,
                              hipStream_t stream) {
    (void)in_sizes; (void)n_in; (void)out_size; (void)ws_size;
    const float* x    = (const float*)d_in[0];
    const float* ef   = (const float*)d_in[1];
    const float* Wq   = (const float*)d_in[2];
    const float* bq   = (const float*)d_in[3];
    const float* Wk   = (const float*)d_in[4];
    const float* bk   = (const float*)d_in[5];
    const float* Wv   = (const float*)d_in[6];
    const float* bv   = (const float*)d_in[7];
    const float* Wlin = (const float*)d_in[8];
    const float* blin = (const float*)d_in[9];
    const float* Weq  = (const float*)d_in[10];
    const float* beq  = (const float*)d_in[11];
    const float* Wev  = (const float*)d_in[12];
    const float* bev  = (const float*)d_in[13];
    const float* Wek  = (const float*)d_in[14];
    const float* bek  = (const float*)d_in[15];
    const float* Wel  = (const float*)d_in[16];
    const float* bel  = (const float*)d_in[17];
    const float* Wele = (const float*)d_in[18];
    const float* bele = (const float*)d_in[19];
    const int* edge_index = (const int*)d_in[20];
    const int* e1 = edge_index + N_EDGES;   // row1 = targets

    float* out_node = (float*)d_out;            // N x 64 fp32
    float* out_edge = (float*)d_out + 640000;   // E x 16 fp32

    // ws: NK bf16 [0,10.24MB) | C->G bf16 [10.24,20.48) | sq fp32 [20.48,23.04)
    char* ws = (char*)d_ws;
    u16*   NK = (u16*)ws;
    u16*   G  = (u16*)(ws + 10240000);
    float* sq = (float*)(ws + 20480000);

    proj2_kernel<<<dim3(157, 16), 256, 0, stream>>>(x, Wk, bk, Wv, bv, NK, G);
    gfold_kernel<<<dim3(157, 8), 256, 0, stream>>>(G, Wlin);
    sqk_kernel<<<dim3(157, 8), 256, 0, stream>>>(x, Wq, bq, NK, e1, sq);
    node_kernel<<<N_NODES, 64, 0, stream>>>(ef, e1, sq, G,
                                            Weq, beq, Wev, bev, Wek, bek,
                                            Wel, bel, Wele, bele, blin,
                                            out_node, out_edge);
}

// Round 19
// 214.996 us; speedup vs baseline: 1.1657x; 1.0399x over previous
//
#include <hip/hip_runtime.h>
#include <hip/hip_bf16.h>

typedef unsigned short u16;
typedef unsigned int   u32;

#define N_NODES 10000
#define N_EDGES 80000

// ---------- bf16 workspace helpers (math = fp32, ws storage = bf16) ----------
__device__ __forceinline__ u16 f2bf(float f) {   // round-to-nearest-even
    union { float f; u32 i; } c; c.f = f;
    u32 u = c.i;
    u32 r = (u + 0x7fffu + ((u >> 16) & 1u)) >> 16;
    return (u16)r;
}
__device__ __forceinline__ float bf2f(u16 u) {
    union { u32 i; float f; } c; c.i = ((u32)u) << 16; return c.f;
}
__device__ __forceinline__ void unpack8(uint4 w, float* v) {
    union { u32 i; float f; } c;
    c.i = w.x << 16; v[0] = c.f; c.i = w.x & 0xffff0000u; v[1] = c.f;
    c.i = w.y << 16; v[2] = c.f; c.i = w.y & 0xffff0000u; v[3] = c.f;
    c.i = w.z << 16; v[4] = c.f; c.i = w.z & 0xffff0000u; v[5] = c.f;
    c.i = w.w << 16; v[6] = c.f; c.i = w.w & 0xffff0000u; v[7] = c.f;
}

// =====================================================================
// projkvg: grid (157, 16).
//   y in [0,8):  NK col-tile y*64:  NK = x @ Wk^T + bk          (bf16 out)
//   y in [8,16): h = y-8: nv-tile (LDS, fp32) = x @ Wv_h^T + bv_h;
//                G-tile = nv-tile @ WlinSlice_h^T               (bf16 out)
// RACE FIX (R18->R19): __syncthreads() before re-staging wt with Wlin.
// =====================================================================
__global__ __launch_bounds__(256) void projkvg_kernel(
    const float* __restrict__ x,
    const float* __restrict__ Wk, const float* __restrict__ bk,
    const float* __restrict__ Wv, const float* __restrict__ bv,
    const float* __restrict__ Wlin,
    u16* __restrict__ NK, u16* __restrict__ G)
{
    __shared__ float xs[64 * 68];
    __shared__ float wt[64 * 68];
    __shared__ float nv[64 * 68];
    const int t   = threadIdx.x;
    const int r0  = blockIdx.x * 64;
    const int cy  = blockIdx.y;
    const bool kq = (cy < 8);
    const int h   = kq ? cy : (cy - 8);
    const int c0  = h * 64;

    const int row = t >> 2, seg = t & 3;
    {   // stage x tile + first weight tile (Wk rows or Wv rows for head h)
        const int r = r0 + row;
        if (r < N_NODES) {
            const float4* p = (const float4*)(x + ((long)r * 64 + seg * 16));
            #pragma unroll
            for (int q4 = 0; q4 < 4; ++q4) *(float4*)&xs[row * 68 + seg * 16 + q4 * 4] = p[q4];
        } else {
            #pragma unroll
            for (int j = 0; j < 16; ++j) xs[row * 68 + seg * 16 + j] = 0.f;
        }
        const float* W = kq ? Wk : Wv;
        const float4* q = (const float4*)(W + ((long)(c0 + row) * 64 + seg * 16));
        #pragma unroll
        for (int q4 = 0; q4 < 4; ++q4) *(float4*)&wt[row * 68 + seg * 16 + q4 * 4] = q[q4];
    }
    __syncthreads();

    const int tc = t & 15, tr = t >> 4;
    float acc[4][4];
    #pragma unroll
    for (int r = 0; r < 4; ++r)
        #pragma unroll
        for (int c = 0; c < 4; ++c) acc[r][c] = 0.f;

    #pragma unroll 4
    for (int k4 = 0; k4 < 16; ++k4) {
        float4 a[4], b4[4];
        #pragma unroll
        for (int r = 0; r < 4; ++r) a[r] = *(const float4*)&xs[(tr * 4 + r) * 68 + k4 * 4];
        #pragma unroll
        for (int c = 0; c < 4; ++c) b4[c] = *(const float4*)&wt[(tc * 4 + c) * 68 + k4 * 4];
        #pragma unroll
        for (int r = 0; r < 4; ++r)
            #pragma unroll
            for (int c = 0; c < 4; ++c)
                acc[r][c] += a[r].x * b4[c].x + a[r].y * b4[c].y + a[r].z * b4[c].z + a[r].w * b4[c].w;
    }

    if (kq) {   // NK path: add bias, store bf16
        #pragma unroll
        for (int r = 0; r < 4; ++r) {
            const int gr = r0 + tr * 4 + r;
            if (gr >= N_NODES) continue;
            const int cb = c0 + tc * 4;
            float v0 = acc[r][0] + bk[cb + 0];
            float v1 = acc[r][1] + bk[cb + 1];
            float v2 = acc[r][2] + bk[cb + 2];
            float v3 = acc[r][3] + bk[cb + 3];
            u32 p0 = (u32)f2bf(v0) | ((u32)f2bf(v1) << 16);
            u32 p1 = (u32)f2bf(v2) | ((u32)f2bf(v3) << 16);
            *(uint2*)(NK + (long)gr * 512 + cb) = make_uint2(p0, p1);
        }
        return;
    }

    // NV->G path: nv tile to LDS (fp32, with bias)
    #pragma unroll
    for (int r = 0; r < 4; ++r)
        #pragma unroll
        for (int c = 0; c < 4; ++c)
            nv[(tr * 4 + r) * 68 + tc * 4 + c] = acc[r][c] + bv[c0 + tc * 4 + c];

    __syncthreads();   // *** FIX: all GEMM1 reads of wt complete before restage ***

    // stage Wlin slice: wt[c][d] = Wlin[c*512 + h*64 + d], c,d in [0,64)
    {
        const float4* q = (const float4*)(Wlin + ((long)row * 512 + c0 + seg * 16));
        #pragma unroll
        for (int q4 = 0; q4 < 4; ++q4) *(float4*)&wt[row * 68 + seg * 16 + q4 * 4] = q[q4];
    }
    __syncthreads();

    // G tile = nv @ WlinSlice^T
    #pragma unroll
    for (int r = 0; r < 4; ++r)
        #pragma unroll
        for (int c = 0; c < 4; ++c) acc[r][c] = 0.f;
    #pragma unroll 4
    for (int k4 = 0; k4 < 16; ++k4) {
        float4 a[4], b4[4];
        #pragma unroll
        for (int r = 0; r < 4; ++r) a[r] = *(const float4*)&nv[(tr * 4 + r) * 68 + k4 * 4];
        #pragma unroll
        for (int c = 0; c < 4; ++c) b4[c] = *(const float4*)&wt[(tc * 4 + c) * 68 + k4 * 4];
        #pragma unroll
        for (int r = 0; r < 4; ++r)
            #pragma unroll
            for (int c = 0; c < 4; ++c)
                acc[r][c] += a[r].x * b4[c].x + a[r].y * b4[c].y + a[r].z * b4[c].z + a[r].w * b4[c].w;
    }

    #pragma unroll
    for (int r = 0; r < 4; ++r) {
        const int gr = r0 + tr * 4 + r;
        if (gr >= N_NODES) continue;
        const int cb = c0 + tc * 4;
        u32 p0 = (u32)f2bf(acc[r][0]) | ((u32)f2bf(acc[r][1]) << 16);
        u32 p1 = (u32)f2bf(acc[r][2]) | ((u32)f2bf(acc[r][3]) << 16);
        *(uint2*)(G + (long)gr * 512 + cb) = make_uint2(p0, p1);
    }
}

// =====================================================================
// sqk: grid (157 node-tiles, 8 heads) — one head per block.
//   sq[e=n*8+i, h] = dot64(q[n,h,:], k[e1[e],h,:]) / 8
// =====================================================================
__global__ __launch_bounds__(256) void sqk_kernel(
    const float* __restrict__ x, const float* __restrict__ Wq, const float* __restrict__ bq,
    const u16* __restrict__ NK, const int* __restrict__ e1, float* __restrict__ sq)
{
    __shared__ float xs[64 * 68];
    __shared__ float wqh[64 * 68];
    __shared__ float qh[64 * 68];
    __shared__ int   tg[512];
    const int t  = threadIdx.x;
    const int n0 = blockIdx.x * 64;
    const int h  = blockIdx.y;

    {
        const int row = t >> 2, seg = t & 3;
        const int r = n0 + row;
        if (r < N_NODES) {
            const float4* p = (const float4*)(x + ((long)r * 64 + seg * 16));
            #pragma unroll
            for (int q4 = 0; q4 < 4; ++q4) *(float4*)&xs[row * 68 + seg * 16 + q4 * 4] = p[q4];
        } else {
            #pragma unroll
            for (int j = 0; j < 16; ++j) xs[row * 68 + seg * 16 + j] = 0.f;
        }
        const float4* q = (const float4*)(Wq + ((long)(h * 64 + row) * 64 + seg * 16));
        #pragma unroll
        for (int q4 = 0; q4 < 4; ++q4) *(float4*)&wqh[row * 68 + seg * 16 + q4 * 4] = q[q4];

        int i0 = t, i1 = t + 256;
        tg[i0] = (n0 * 8 + i0 < N_EDGES) ? e1[n0 * 8 + i0] : 0;
        tg[i1] = (n0 * 8 + i1 < N_EDGES) ? e1[n0 * 8 + i1] : 0;
    }
    __syncthreads();

    const int tc = t & 15, tr = t >> 4;
    float acc[4][4];
    #pragma unroll
    for (int r = 0; r < 4; ++r)
        #pragma unroll
        for (int c = 0; c < 4; ++c) acc[r][c] = 0.f;
    #pragma unroll 4
    for (int k4 = 0; k4 < 16; ++k4) {
        float4 a[4], b4[4];
        #pragma unroll
        for (int r = 0; r < 4; ++r) a[r] = *(const float4*)&xs[(tr * 4 + r) * 68 + k4 * 4];
        #pragma unroll
        for (int c = 0; c < 4; ++c) b4[c] = *(const float4*)&wqh[(tc * 4 + c) * 68 + k4 * 4];
        #pragma unroll
        for (int r = 0; r < 4; ++r)
            #pragma unroll
            for (int c = 0; c < 4; ++c)
                acc[r][c] += a[r].x * b4[c].x + a[r].y * b4[c].y + a[r].z * b4[c].z + a[r].w * b4[c].w;
    }
    #pragma unroll
    for (int r = 0; r < 4; ++r)
        #pragma unroll
        for (int c = 0; c < 4; ++c)
            qh[(tr * 4 + r) * 68 + tc * 4 + c] = acc[r][c] + bq[h * 64 + tc * 4 + c];
    __syncthreads();

    #pragma unroll
    for (int rep = 0; rep < 2; ++rep) {
        const int p = rep * 256 + t;
        const int nl = p >> 3, i = p & 7;
        if (n0 + nl < N_NODES) {
            const int kr = tg[p];
            const uint4* kp = (const uint4*)(NK + ((long)kr * 512 + h * 64));
            float d = 0.f;
            #pragma unroll
            for (int q4 = 0; q4 < 8; ++q4) {
                float kv[8]; unpack8(kp[q4], kv);
                const float* qp = &qh[nl * 68 + q4 * 8];
                #pragma unroll
                for (int j = 0; j < 8; ++j) d += qp[j] * kv[j];
            }
            sq[(long)(n0 + nl) * 64 + i * 8 + h] = d * 0.125f;
        }
    }
}

// =====================================================================
// node kernel: one block (64 threads) per node; fp32 outputs.
// =====================================================================
__global__ __launch_bounds__(64) void node_kernel(
    const float* __restrict__ ef, const int* __restrict__ e1,
    const float* __restrict__ sq, const u16* __restrict__ G,
    const float* __restrict__ Weq, const float* __restrict__ beq,
    const float* __restrict__ Wev, const float* __restrict__ bev,
    const float* __restrict__ Wek, const float* __restrict__ bek,
    const float* __restrict__ Wel, const float* __restrict__ bel,
    const float* __restrict__ Wele, const float* __restrict__ bele,
    const float* __restrict__ blin,
    float* __restrict__ out_node, float* __restrict__ out_edge)
{
    __shared__ float sqk_l[64];
    __shared__ float efl[128];
    __shared__ float eqb[8 * 68], ekb[8 * 68], evb[8 * 68], eob[8 * 68];
    __shared__ float sl[8 * 36];
    __shared__ float well[8 * 65];
    __shared__ float emb_l[64];
    __shared__ float attn_l[64];
    __shared__ int   tgt[8];

    const int t = threadIdx.x;
    const int n = blockIdx.x;

    if (t < 8) tgt[t] = e1[n * 8 + t];
    sqk_l[t] = sq[(long)n * 64 + t];
    {
        const float2* p = (const float2*)(ef + (long)n * 128);
        float2 w = p[t];
        efl[2 * t] = w.x; efl[2 * t + 1] = w.y;
    }
    for (int idx = t; idx < 512; idx += 64)
        well[(idx >> 6) * 65 + (idx & 63)] = Wel[idx];
    __syncthreads();

    float wq16[16], wv16[16], wk8[8];
    {
        const float4* p = (const float4*)(Weq + t * 16);
        #pragma unroll
        for (int q4 = 0; q4 < 4; ++q4) *(float4*)&wq16[q4 * 4] = p[q4];
        const float4* q = (const float4*)(Wev + t * 16);
        #pragma unroll
        for (int q4 = 0; q4 < 4; ++q4) *(float4*)&wv16[q4 * 4] = q[q4];
        const float4* r = (const float4*)(Wek + t * 8);
        *(float4*)&wk8[0] = r[0]; *(float4*)&wk8[4] = r[1];
    }
    const float beqv = beq[t], bevv = bev[t], bekv = bek[t];

    #pragma unroll
    for (int i = 0; i < 8; ++i) {
        float aq = beqv, av = bevv;
        #pragma unroll
        for (int c = 0; c < 16; ++c) { float f = efl[i * 16 + c]; aq += f * wq16[c]; av += f * wv16[c]; }
        float ak = bekv;
        #pragma unroll
        for (int c = 0; c < 8; ++c) ak += sqk_l[i * 8 + c] * wk8[c];
        eqb[i * 68 + t] = aq; evb[i * 68 + t] = av; ekb[i * 68 + t] = ak;
    }
    __syncthreads();

    {
        const int i = t >> 3, j = t & 7;
        #pragma unroll
        for (int eh = 0; eh < 4; ++eh) {
            float acc = 0.f;
            #pragma unroll
            for (int de = 0; de < 16; ++de)
                acc += eqb[i * 68 + eh * 16 + de] * ekb[j * 68 + eh * 16 + de];
            sl[i * 36 + j * 4 + eh] = acc * 0.25f;
        }
    }
    __syncthreads();

    if (t < 32) {
        const int i = t >> 2, eh = t & 3;
        float mx = -1e30f;
        #pragma unroll
        for (int j = 0; j < 8; ++j) mx = fmaxf(mx, sl[i * 36 + j * 4 + eh]);
        float sum = 0.f;
        #pragma unroll
        for (int j = 0; j < 8; ++j) { float e = __expf(sl[i * 36 + j * 4 + eh] - mx); sl[i * 36 + j * 4 + eh] = e; sum += e; }
        float inv = 1.f / (sum + 1e-16f);
        #pragma unroll
        for (int j = 0; j < 8; ++j) sl[i * 36 + j * 4 + eh] *= inv;
    }
    __syncthreads();

    {
        const int eh = t >> 4;
        #pragma unroll
        for (int i = 0; i < 8; ++i) {
            float acc = 0.f;
            #pragma unroll
            for (int j = 0; j < 8; ++j) acc += sl[i * 36 + j * 4 + eh] * evb[j * 68 + t];
            eob[i * 68 + t] = acc;
        }
    }
    __syncthreads();

    {
        const int i = t >> 3, h = t & 7;
        float acc = bel[h];
        #pragma unroll 8
        for (int c = 0; c < 64; ++c) acc += eob[i * 68 + c] * well[h * 65 + c];
        emb_l[i * 8 + h] = acc;
    }
    __syncthreads();

    #pragma unroll
    for (int rep = 0; rep < 2; ++rep) {
        const int idx = rep * 64 + t;
        const int i = idx >> 4, de = idx & 15;
        float acc = bele[de];
        #pragma unroll
        for (int h = 0; h < 8; ++h) acc += emb_l[i * 8 + h] * Wele[de * 8 + h];
        out_edge[(long)n * 128 + idx] = acc;
    }

    if (t < 8) {
        const int h = t;
        float l[8], mx = -1e30f;
        #pragma unroll
        for (int i = 0; i < 8; ++i) { l[i] = emb_l[i * 8 + h] + sqk_l[i * 8 + h]; mx = fmaxf(mx, l[i]); }
        float sum = 0.f;
        #pragma unroll
        for (int i = 0; i < 8; ++i) { float e = __expf(l[i] - mx); attn_l[i * 8 + h] = e; sum += e; }
        float inv = 1.f / (sum + 1e-16f);
        #pragma unroll
        for (int i = 0; i < 8; ++i) attn_l[i * 8 + h] *= inv;
    }
    __syncthreads();

    {
        float acc = blin[t];
        #pragma unroll
        for (int i = 0; i < 8; ++i) {
            const u16* gr = G + (long)tgt[i] * 512;
            #pragma unroll
            for (int h = 0; h < 8; ++h)
                acc += attn_l[i * 8 + h] * bf2f(gr[h * 64 + t]);
        }
        out_node[(long)n * 64 + t] = acc;
    }
}

extern "C" void kernel_launch(void* const* d_in, const int* in_sizes, int n_in,
                              void* d_out, int out_size, void* d_ws, size_t ws_size,
                              hipStream_t stream) {
    (void)in_sizes; (void)n_in; (void)out_size; (void)ws_size;
    const float* x    = (const float*)d_in[0];
    const float* ef   = (const float*)d_in[1];
    const float* Wq   = (const float*)d_in[2];
    const float* bq   = (const float*)d_in[3];
    const float* Wk   = (const float*)d_in[4];
    const float* bk   = (const float*)d_in[5];
    const float* Wv   = (const float*)d_in[6];
    const float* bv   = (const float*)d_in[7];
    const float* Wlin = (const float*)d_in[8];
    const float* blin = (const float*)d_in[9];
    const float* Weq  = (const float*)d_in[10];
    const float* beq  = (const float*)d_in[11];
    const float* Wev  = (const float*)d_in[12];
    const float* bev  = (const float*)d_in[13];
    const float* Wek  = (const float*)d_in[14];
    const float* bek  = (const float*)d_in[15];
    const float* Wel  = (const float*)d_in[16];
    const float* bel  = (const float*)d_in[17];
    const float* Wele = (const float*)d_in[18];
    const float* bele = (const float*)d_in[19];
    const int* edge_index = (const int*)d_in[20];
    const int* e1 = edge_index + N_EDGES;   // row1 = targets

    float* out_node = (float*)d_out;            // N x 64 fp32
    float* out_edge = (float*)d_out + 640000;   // E x 16 fp32

    // ws: NK bf16 [0,10.24MB) | G bf16 [10.24,20.48) | sq fp32 [20.48,23.04)
    char* ws = (char*)d_ws;
    u16*   NK = (u16*)ws;
    u16*   G  = (u16*)(ws + 10240000);
    float* sq = (float*)(ws + 20480000);

    projkvg_kernel<<<dim3(157, 16), 256, 0, stream>>>(x, Wk, bk, Wv, bv, Wlin, NK, G);
    sqk_kernel<<<dim3(157, 8), 256, 0, stream>>>(x, Wq, bq, NK, e1, sq);
    node_kernel<<<N_NODES, 64, 0, stream>>>(ef, e1, sq, G,
                                            Weq, beq, Wev, bev, Wek, bek,
                                            Wel, bel, Wele, bele, blin,
                                            out_node, out_edge);
}

// Round 20
// 205.122 us; speedup vs baseline: 1.2218x; 1.0481x over previous
//
#include <hip/hip_runtime.h>
#include <hip/hip_bf16.h>

typedef unsigned short u16;
typedef unsigned int   u32;

#define N_NODES 10000
#define N_EDGES 80000

// ---------- bf16 workspace helpers (math = fp32, ws storage = bf16) ----------
__device__ __forceinline__ u16 f2bf(float f) {   // round-to-nearest-even
    union { float f; u32 i; } c; c.f = f;
    u32 u = c.i;
    u32 r = (u + 0x7fffu + ((u >> 16) & 1u)) >> 16;
    return (u16)r;
}
__device__ __forceinline__ float bf2f(u16 u) {
    union { u32 i; float f; } c; c.i = ((u32)u) << 16; return c.f;
}
__device__ __forceinline__ void unpack8(uint4 w, float* v) {
    union { u32 i; float f; } c;
    c.i = w.x << 16; v[0] = c.f; c.i = w.x & 0xffff0000u; v[1] = c.f;
    c.i = w.y << 16; v[2] = c.f; c.i = w.y & 0xffff0000u; v[3] = c.f;
    c.i = w.z << 16; v[4] = c.f; c.i = w.z & 0xffff0000u; v[5] = c.f;
    c.i = w.w << 16; v[6] = c.f; c.i = w.w & 0xffff0000u; v[7] = c.f;
}

// =====================================================================
// projkvg: grid (157, 16).
//   y in [0,8):  NK col-tile y*64:  NK = x @ Wk^T + bk          (bf16 out)
//   y in [8,16): h = y-8: nv-tile (LDS, fp32) = x @ Wv_h^T + bv_h;
//                G-tile = nv-tile @ WlinSlice_h^T               (bf16 out)
// R19->R20: strided-16 micro-tile (rows r*16+tr, cols c*16+tc) —
// B-operand LDS reads go 8-way -> 2-way bank conflicts.
// =====================================================================
__global__ __launch_bounds__(256) void projkvg_kernel(
    const float* __restrict__ x,
    const float* __restrict__ Wk, const float* __restrict__ bk,
    const float* __restrict__ Wv, const float* __restrict__ bv,
    const float* __restrict__ Wlin,
    u16* __restrict__ NK, u16* __restrict__ G)
{
    __shared__ float xs[64 * 68];
    __shared__ float wt[64 * 68];
    __shared__ float nv[64 * 68];
    const int t   = threadIdx.x;
    const int r0  = blockIdx.x * 64;
    const int cy  = blockIdx.y;
    const bool kq = (cy < 8);
    const int h   = kq ? cy : (cy - 8);
    const int c0  = h * 64;

    const int row = t >> 2, seg = t & 3;
    {   // stage x tile + first weight tile (Wk rows or Wv rows for head h)
        const int r = r0 + row;
        if (r < N_NODES) {
            const float4* p = (const float4*)(x + ((long)r * 64 + seg * 16));
            #pragma unroll
            for (int q4 = 0; q4 < 4; ++q4) *(float4*)&xs[row * 68 + seg * 16 + q4 * 4] = p[q4];
        } else {
            #pragma unroll
            for (int j = 0; j < 16; ++j) xs[row * 68 + seg * 16 + j] = 0.f;
        }
        const float* W = kq ? Wk : Wv;
        const float4* q = (const float4*)(W + ((long)(c0 + row) * 64 + seg * 16));
        #pragma unroll
        for (int q4 = 0; q4 < 4; ++q4) *(float4*)&wt[row * 68 + seg * 16 + q4 * 4] = q[q4];
    }
    __syncthreads();

    const int tc = t & 15, tr = t >> 4;
    float acc[4][4];
    #pragma unroll
    for (int r = 0; r < 4; ++r)
        #pragma unroll
        for (int c = 0; c < 4; ++c) acc[r][c] = 0.f;

    #pragma unroll 4
    for (int k4 = 0; k4 < 16; ++k4) {
        float4 a[4], b4[4];
        #pragma unroll
        for (int r = 0; r < 4; ++r) a[r] = *(const float4*)&xs[(r * 16 + tr) * 68 + k4 * 4];
        #pragma unroll
        for (int c = 0; c < 4; ++c) b4[c] = *(const float4*)&wt[(c * 16 + tc) * 68 + k4 * 4];
        #pragma unroll
        for (int r = 0; r < 4; ++r)
            #pragma unroll
            for (int c = 0; c < 4; ++c)
                acc[r][c] += a[r].x * b4[c].x + a[r].y * b4[c].y + a[r].z * b4[c].z + a[r].w * b4[c].w;
    }

    if (kq) {   // NK path: add bias, store bf16 (scalar u16, 32B-contig per row-group)
        #pragma unroll
        for (int r = 0; r < 4; ++r) {
            const int gr = r0 + r * 16 + tr;
            if (gr >= N_NODES) continue;
            #pragma unroll
            for (int c = 0; c < 4; ++c) {
                const int col = c0 + c * 16 + tc;
                NK[(long)gr * 512 + col] = f2bf(acc[r][c] + bk[col]);
            }
        }
        return;
    }

    // NV->G path: nv tile to LDS (fp32, with bias)
    #pragma unroll
    for (int r = 0; r < 4; ++r)
        #pragma unroll
        for (int c = 0; c < 4; ++c)
            nv[(r * 16 + tr) * 68 + c * 16 + tc] = acc[r][c] + bv[c0 + c * 16 + tc];

    __syncthreads();   // all GEMM1 reads of wt complete before restage

    // stage Wlin slice: wt[c][d] = Wlin[c*512 + h*64 + d], c,d in [0,64)
    {
        const float4* q = (const float4*)(Wlin + ((long)row * 512 + c0 + seg * 16));
        #pragma unroll
        for (int q4 = 0; q4 < 4; ++q4) *(float4*)&wt[row * 68 + seg * 16 + q4 * 4] = q[q4];
    }
    __syncthreads();

    // G tile = nv @ WlinSlice^T
    #pragma unroll
    for (int r = 0; r < 4; ++r)
        #pragma unroll
        for (int c = 0; c < 4; ++c) acc[r][c] = 0.f;
    #pragma unroll 4
    for (int k4 = 0; k4 < 16; ++k4) {
        float4 a[4], b4[4];
        #pragma unroll
        for (int r = 0; r < 4; ++r) a[r] = *(const float4*)&nv[(r * 16 + tr) * 68 + k4 * 4];
        #pragma unroll
        for (int c = 0; c < 4; ++c) b4[c] = *(const float4*)&wt[(c * 16 + tc) * 68 + k4 * 4];
        #pragma unroll
        for (int r = 0; r < 4; ++r)
            #pragma unroll
            for (int c = 0; c < 4; ++c)
                acc[r][c] += a[r].x * b4[c].x + a[r].y * b4[c].y + a[r].z * b4[c].z + a[r].w * b4[c].w;
    }

    #pragma unroll
    for (int r = 0; r < 4; ++r) {
        const int gr = r0 + r * 16 + tr;
        if (gr >= N_NODES) continue;
        #pragma unroll
        for (int c = 0; c < 4; ++c) {
            const int col = c0 + c * 16 + tc;
            G[(long)gr * 512 + col] = f2bf(acc[r][c]);
        }
    }
}

// =====================================================================
// sqk: grid (157 node-tiles, 8 heads) — one head per block.
//   sq[e=n*8+i, h] = dot64(q[n,h,:], k[e1[e],h,:]) / 8
// Strided-16 micro-tile in the q GEMM (bank-conflict fix).
// =====================================================================
__global__ __launch_bounds__(256) void sqk_kernel(
    const float* __restrict__ x, const float* __restrict__ Wq, const float* __restrict__ bq,
    const u16* __restrict__ NK, const int* __restrict__ e1, float* __restrict__ sq)
{
    __shared__ float xs[64 * 68];
    __shared__ float wqh[64 * 68];
    __shared__ float qh[64 * 68];
    __shared__ int   tg[512];
    const int t  = threadIdx.x;
    const int n0 = blockIdx.x * 64;
    const int h  = blockIdx.y;

    {
        const int row = t >> 2, seg = t & 3;
        const int r = n0 + row;
        if (r < N_NODES) {
            const float4* p = (const float4*)(x + ((long)r * 64 + seg * 16));
            #pragma unroll
            for (int q4 = 0; q4 < 4; ++q4) *(float4*)&xs[row * 68 + seg * 16 + q4 * 4] = p[q4];
        } else {
            #pragma unroll
            for (int j = 0; j < 16; ++j) xs[row * 68 + seg * 16 + j] = 0.f;
        }
        const float4* q = (const float4*)(Wq + ((long)(h * 64 + row) * 64 + seg * 16));
        #pragma unroll
        for (int q4 = 0; q4 < 4; ++q4) *(float4*)&wqh[row * 68 + seg * 16 + q4 * 4] = q[q4];

        int i0 = t, i1 = t + 256;
        tg[i0] = (n0 * 8 + i0 < N_EDGES) ? e1[n0 * 8 + i0] : 0;
        tg[i1] = (n0 * 8 + i1 < N_EDGES) ? e1[n0 * 8 + i1] : 0;
    }
    __syncthreads();

    const int tc = t & 15, tr = t >> 4;
    float acc[4][4];
    #pragma unroll
    for (int r = 0; r < 4; ++r)
        #pragma unroll
        for (int c = 0; c < 4; ++c) acc[r][c] = 0.f;
    #pragma unroll 4
    for (int k4 = 0; k4 < 16; ++k4) {
        float4 a[4], b4[4];
        #pragma unroll
        for (int r = 0; r < 4; ++r) a[r] = *(const float4*)&xs[(r * 16 + tr) * 68 + k4 * 4];
        #pragma unroll
        for (int c = 0; c < 4; ++c) b4[c] = *(const float4*)&wqh[(c * 16 + tc) * 68 + k4 * 4];
        #pragma unroll
        for (int r = 0; r < 4; ++r)
            #pragma unroll
            for (int c = 0; c < 4; ++c)
                acc[r][c] += a[r].x * b4[c].x + a[r].y * b4[c].y + a[r].z * b4[c].z + a[r].w * b4[c].w;
    }
    #pragma unroll
    for (int r = 0; r < 4; ++r)
        #pragma unroll
        for (int c = 0; c < 4; ++c)
            qh[(r * 16 + tr) * 68 + c * 16 + tc] = acc[r][c] + bq[h * 64 + c * 16 + tc];
    __syncthreads();

    #pragma unroll
    for (int rep = 0; rep < 2; ++rep) {
        const int p = rep * 256 + t;
        const int nl = p >> 3, i = p & 7;
        if (n0 + nl < N_NODES) {
            const int kr = tg[p];
            const uint4* kp = (const uint4*)(NK + ((long)kr * 512 + h * 64));
            float d = 0.f;
            #pragma unroll
            for (int q4 = 0; q4 < 8; ++q4) {
                float kv[8]; unpack8(kp[q4], kv);
                const float* qp = &qh[nl * 68 + q4 * 8];
                #pragma unroll
                for (int j = 0; j < 8; ++j) d += qp[j] * kv[j];
            }
            sq[(long)(n0 + nl) * 64 + i * 8 + h] = d * 0.125f;
        }
    }
}

// =====================================================================
// node kernel: one block (64 threads) per node; fp32 outputs.
// =====================================================================
__global__ __launch_bounds__(64) void node_kernel(
    const float* __restrict__ ef, const int* __restrict__ e1,
    const float* __restrict__ sq, const u16* __restrict__ G,
    const float* __restrict__ Weq, const float* __restrict__ beq,
    const float* __restrict__ Wev, const float* __restrict__ bev,
    const float* __restrict__ Wek, const float* __restrict__ bek,
    const float* __restrict__ Wel, const float* __restrict__ bel,
    const float* __restrict__ Wele, const float* __restrict__ bele,
    const float* __restrict__ blin,
    float* __restrict__ out_node, float* __restrict__ out_edge)
{
    __shared__ float sqk_l[64];
    __shared__ float efl[128];
    __shared__ float eqb[8 * 68], ekb[8 * 68], evb[8 * 68], eob[8 * 68];
    __shared__ float sl[8 * 36];
    __shared__ float well[8 * 65];
    __shared__ float emb_l[64];
    __shared__ float attn_l[64];
    __shared__ int   tgt[8];

    const int t = threadIdx.x;
    const int n = blockIdx.x;

    if (t < 8) tgt[t] = e1[n * 8 + t];
    sqk_l[t] = sq[(long)n * 64 + t];
    {
        const float2* p = (const float2*)(ef + (long)n * 128);
        float2 w = p[t];
        efl[2 * t] = w.x; efl[2 * t + 1] = w.y;
    }
    for (int idx = t; idx < 512; idx += 64)
        well[(idx >> 6) * 65 + (idx & 63)] = Wel[idx];
    __syncthreads();

    float wq16[16], wv16[16], wk8[8];
    {
        const float4* p = (const float4*)(Weq + t * 16);
        #pragma unroll
        for (int q4 = 0; q4 < 4; ++q4) *(float4*)&wq16[q4 * 4] = p[q4];
        const float4* q = (const float4*)(Wev + t * 16);
        #pragma unroll
        for (int q4 = 0; q4 < 4; ++q4) *(float4*)&wv16[q4 * 4] = q[q4];
        const float4* r = (const float4*)(Wek + t * 8);
        *(float4*)&wk8[0] = r[0]; *(float4*)&wk8[4] = r[1];
    }
    const float beqv = beq[t], bevv = bev[t], bekv = bek[t];

    #pragma unroll
    for (int i = 0; i < 8; ++i) {
        float aq = beqv, av = bevv;
        #pragma unroll
        for (int c = 0; c < 16; ++c) { float f = efl[i * 16 + c]; aq += f * wq16[c]; av += f * wv16[c]; }
        float ak = bekv;
        #pragma unroll
        for (int c = 0; c < 8; ++c) ak += sqk_l[i * 8 + c] * wk8[c];
        eqb[i * 68 + t] = aq; evb[i * 68 + t] = av; ekb[i * 68 + t] = ak;
    }
    __syncthreads();

    {
        const int i = t >> 3, j = t & 7;
        #pragma unroll
        for (int eh = 0; eh < 4; ++eh) {
            float acc = 0.f;
            #pragma unroll
            for (int de = 0; de < 16; ++de)
                acc += eqb[i * 68 + eh * 16 + de] * ekb[j * 68 + eh * 16 + de];
            sl[i * 36 + j * 4 + eh] = acc * 0.25f;
        }
    }
    __syncthreads();

    if (t < 32) {
        const int i = t >> 2, eh = t & 3;
        float mx = -1e30f;
        #pragma unroll
        for (int j = 0; j < 8; ++j) mx = fmaxf(mx, sl[i * 36 + j * 4 + eh]);
        float sum = 0.f;
        #pragma unroll
        for (int j = 0; j < 8; ++j) { float e = __expf(sl[i * 36 + j * 4 + eh] - mx); sl[i * 36 + j * 4 + eh] = e; sum += e; }
        float inv = 1.f / (sum + 1e-16f);
        #pragma unroll
        for (int j = 0; j < 8; ++j) sl[i * 36 + j * 4 + eh] *= inv;
    }
    __syncthreads();

    {
        const int eh = t >> 4;
        #pragma unroll
        for (int i = 0; i < 8; ++i) {
            float acc = 0.f;
            #pragma unroll
            for (int j = 0; j < 8; ++j) acc += sl[i * 36 + j * 4 + eh] * evb[j * 68 + t];
            eob[i * 68 + t] = acc;
        }
    }
    __syncthreads();

    {
        const int i = t >> 3, h = t & 7;
        float acc = bel[h];
        #pragma unroll 8
        for (int c = 0; c < 64; ++c) acc += eob[i * 68 + c] * well[h * 65 + c];
        emb_l[i * 8 + h] = acc;
    }
    __syncthreads();

    #pragma unroll
    for (int rep = 0; rep < 2; ++rep) {
        const int idx = rep * 64 + t;
        const int i = idx >> 4, de = idx & 15;
        float acc = bele[de];
        #pragma unroll
        for (int h = 0; h < 8; ++h) acc += emb_l[i * 8 + h] * Wele[de * 8 + h];
        out_edge[(long)n * 128 + idx] = acc;
    }

    if (t < 8) {
        const int h = t;
        float l[8], mx = -1e30f;
        #pragma unroll
        for (int i = 0; i < 8; ++i) { l[i] = emb_l[i * 8 + h] + sqk_l[i * 8 + h]; mx = fmaxf(mx, l[i]); }
        float sum = 0.f;
        #pragma unroll
        for (int i = 0; i < 8; ++i) { float e = __expf(l[i] - mx); attn_l[i * 8 + h] = e; sum += e; }
        float inv = 1.f / (sum + 1e-16f);
        #pragma unroll
        for (int i = 0; i < 8; ++i) attn_l[i * 8 + h] *= inv;
    }
    __syncthreads();

    {
        float acc = blin[t];
        #pragma unroll
        for (int i = 0; i < 8; ++i) {
            const u16* gr = G + (long)tgt[i] * 512;
            #pragma unroll
            for (int h = 0; h < 8; ++h)
                acc += attn_l[i * 8 + h] * bf2f(gr[h * 64 + t]);
        }
        out_node[(long)n * 64 + t] = acc;
    }
}

extern "C" void kernel_launch(void* const* d_in, const int* in_sizes, int n_in,
                              void* d_out, int out_size, void* d_ws, size_t ws_size,
                              hipStream_t stream) {
    (void)in_sizes; (void)n_in; (void)out_size; (void)ws_size;
    const float* x    = (const float*)d_in[0];
    const float* ef   = (const float*)d_in[1];
    const float* Wq   = (const float*)d_in[2];
    const float* bq   = (const float*)d_in[3];
    const float* Wk   = (const float*)d_in[4];
    const float* bk   = (const float*)d_in[5];
    const float* Wv   = (const float*)d_in[6];
    const float* bv   = (const float*)d_in[7];
    const float* Wlin = (const float*)d_in[8];
    const float* blin = (const float*)d_in[9];
    const float* Weq  = (const float*)d_in[10];
    const float* beq  = (const float*)d_in[11];
    const float* Wev  = (const float*)d_in[12];
    const float* bev  = (const float*)d_in[13];
    const float* Wek  = (const float*)d_in[14];
    const float* bek  = (const float*)d_in[15];
    const float* Wel  = (const float*)d_in[16];
    const float* bel  = (const float*)d_in[17];
    const float* Wele = (const float*)d_in[18];
    const float* bele = (const float*)d_in[19];
    const int* edge_index = (const int*)d_in[20];
    const int* e1 = edge_index + N_EDGES;   // row1 = targets

    float* out_node = (float*)d_out;            // N x 64 fp32
    float* out_edge = (float*)d_out + 640000;   // E x 16 fp32

    // ws: NK bf16 [0,10.24MB) | G bf16 [10.24,20.48) | sq fp32 [20.48,23.04)
    char* ws = (char*)d_ws;
    u16*   NK = (u16*)ws;
    u16*   G  = (u16*)(ws + 10240000);
    float* sq = (float*)(ws + 20480000);

    projkvg_kernel<<<dim3(157, 16), 256, 0, stream>>>(x, Wk, bk, Wv, bv, Wlin, NK, G);
    sqk_kernel<<<dim3(157, 8), 256, 0, stream>>>(x, Wq, bq, NK, e1, sq);
    node_kernel<<<N_NODES, 64, 0, stream>>>(ef, e1, sq, G,
                                            Weq, beq, Wev, bev, Wek, bek,
                                            Wel, bel, Wele, bele, blin,
                                            out_node, out_edge);
}